// Round 1
// baseline (820.351 us; speedup 1.0000x reference)
//
#include <hip/hip_runtime.h>

// Problem constants
#define BB 8
#define LL 1024
#define KNB 30
#define NUM_RBF 16
#define NPOS 16
#define MAXREL 32
#define EDGE_C 128
#define EDGE_IN 416   // NPOS + 25*NUM_RBF

__constant__ int PAIR_I_d[25] = {0,1,2,3,4,0,0,0,0,1,1,1,4,4,3,1,2,3,4,2,3,4,2,3,2};
__constant__ int PAIR_J_d[25] = {0,1,2,3,4,1,2,3,4,2,3,4,2,3,2,0,0,0,0,1,1,1,4,4,3};

__device__ __forceinline__ unsigned long long shfl_down_u64(unsigned long long v, int o) {
    unsigned int lo = (unsigned int)(v & 0xFFFFFFFFull);
    unsigned int hi = (unsigned int)(v >> 32);
    lo = __shfl_down(lo, o);
    hi = __shfl_down(hi, o);
    return ((unsigned long long)hi << 32) | lo;
}
__device__ __forceinline__ unsigned long long shfl_bcast_u64(unsigned long long v, int src) {
    unsigned int lo = (unsigned int)(v & 0xFFFFFFFFull);
    unsigned int hi = (unsigned int)(v >> 32);
    lo = __shfl(lo, src);
    hi = __shfl(hi, src);
    return ((unsigned long long)hi << 32) | lo;
}

// -------- Kernel 1: kNN (one wave per (b,i) row) --------
// Writes E_idx as float into out_idx[row*30 + k].
__global__ __launch_bounds__(64) void knn_kernel(const float* __restrict__ X,
                                                 const float* __restrict__ mask,
                                                 float* __restrict__ out_idx) {
    int row = blockIdx.x;           // b*L + i
    int b = row >> 10;
    int i = row & 1023;
    int lane = threadIdx.x;         // 0..63

    __shared__ float sCa[LL * 3];
    __shared__ float sMask[LL];

    for (int j = lane; j < LL; j += 64) {
        int base = (b * LL + j) * 12 + 3;   // X[b,j,1,:] (Ca)
        sCa[j * 3 + 0] = X[base + 0];
        sCa[j * 3 + 1] = X[base + 1];
        sCa[j * 3 + 2] = X[base + 2];
        sMask[j] = mask[b * LL + j];
    }
    __syncthreads();

    float cax = sCa[i * 3 + 0], cay = sCa[i * 3 + 1], caz = sCa[i * 3 + 2];
    float mi = sMask[i];

    float Dloc[16];
    float dmax = 0.0f;
#pragma unroll
    for (int c = 0; c < 16; ++c) {
        int j = lane + c * 64;
        float dx = cax - sCa[j * 3 + 0];
        float dy = cay - sCa[j * 3 + 1];
        float dz = caz - sCa[j * 3 + 2];
        float m2 = mi * sMask[j];
        float D = m2 * sqrtf(dx * dx + dy * dy + dz * dz + 1e-6f);
        Dloc[c] = D;
        dmax = fmaxf(dmax, D);
    }
    // wave max -> D_max for this row
    for (int o = 32; o; o >>= 1) dmax = fmaxf(dmax, __shfl_down(dmax, o));
    dmax = __shfl(dmax, 0);

    unsigned long long packed[16];
#pragma unroll
    for (int c = 0; c < 16; ++c) {
        int j = lane + c * 64;
        float m2 = mi * sMask[j];
        float Dadj = Dloc[c] + (1.0f - m2) * dmax;
        unsigned int bits = __float_as_uint(Dadj);   // Dadj >= 0 -> bit order == value order
        packed[c] = ((unsigned long long)bits << 32) | (unsigned int)j;
    }

    float* dst = out_idx + (size_t)row * KNB;
    for (int r = 0; r < KNB; ++r) {
        unsigned long long best = packed[0];
#pragma unroll
        for (int c = 1; c < 16; ++c) best = (packed[c] < best) ? packed[c] : best;
        for (int o = 32; o; o >>= 1) {
            unsigned long long other = shfl_down_u64(best, o);
            best = (other < best) ? other : best;
        }
        best = shfl_bcast_u64(best, 0);
        unsigned int jwin = (unsigned int)(best & 0xFFFFFFFFull);
        // owner lane clears its candidate (static indices -> stays in VGPRs)
#pragma unroll
        for (int c = 0; c < 16; ++c) {
            if ((unsigned int)(lane + c * 64) == jwin) packed[c] = ~0ull;
        }
        if (lane == 0) dst[r] = (float)jwin;
    }
}

// -------- Kernel 2: features + 416x128 projection + LayerNorm --------
// One block (256 threads) per (b,i).
__global__ __launch_bounds__(256) void edge_kernel(const float* __restrict__ X,
                                                   const int* __restrict__ ridx,
                                                   const float* __restrict__ W_pos,
                                                   const float* __restrict__ b_pos,
                                                   const float* __restrict__ W_edge,
                                                   const float* __restrict__ gamma,
                                                   const float* __restrict__ beta,
                                                   const float* __restrict__ out_idx,
                                                   float* __restrict__ out_E) {
    int row = blockIdx.x;   // b*L + i
    int b = row >> 10;
    int i = row & 1023;
    int tid = threadIdx.x;

    __shared__ float f[32 * EDGE_IN];      // padded to 32 edges (rows 30,31 zero)
    __shared__ float atoms[31 * 15];       // [res 0 = i, res 1+k = nbr k][atom Ca,N,C,O,Cb][xyz]
    __shared__ float dist[KNB * 25];
    __shared__ int nbr[KNB];
    __shared__ int dclip[KNB];

    // step 0: neighbor indices + positional bucket
    if (tid < KNB) {
        int jn = (int)out_idx[(size_t)row * KNB + tid];
        nbr[tid] = jn;
        int off = ridx[row] - ridx[b * LL + jn];
        int d = off + MAXREL;
        d = d < 0 ? 0 : (d > 2 * MAXREL ? 2 * MAXREL : d);
        dclip[tid] = d;
    }
    __syncthreads();

    // step 1: atoms for residue i and its 30 neighbors
    if (tid < 31) {
        int r = (tid == 0) ? i : nbr[tid - 1];
        int base = (b * LL + r) * 12;
        float Nx = X[base + 0], Ny = X[base + 1], Nz = X[base + 2];
        float Cax = X[base + 3], Cay = X[base + 4], Caz = X[base + 5];
        float Cx = X[base + 6], Cy = X[base + 7], Cz = X[base + 8];
        float Ox = X[base + 9], Oy = X[base + 10], Oz = X[base + 11];
        float bx = Cax - Nx, by = Cay - Ny, bz = Caz - Nz;
        float cx = Cx - Cax, cy = Cy - Cay, cz = Cz - Caz;
        float ax = by * cz - bz * cy;
        float ay = bz * cx - bx * cz;
        float az = bx * cy - by * cx;
        float Cbx = -0.58273431f * ax + 0.56802827f * bx - 0.54067466f * cx + Cax;
        float Cby = -0.58273431f * ay + 0.56802827f * by - 0.54067466f * cy + Cay;
        float Cbz = -0.58273431f * az + 0.56802827f * bz - 0.54067466f * cz + Caz;
        float* A = &atoms[tid * 15];
        A[0] = Cax; A[1] = Cay; A[2] = Caz;
        A[3] = Nx;  A[4] = Ny;  A[5] = Nz;
        A[6] = Cx;  A[7] = Cy;  A[8] = Cz;
        A[9] = Ox;  A[10] = Oy; A[11] = Oz;
        A[12] = Cbx; A[13] = Cby; A[14] = Cbz;
    }
    __syncthreads();

    // step 2: 30*25 atom-pair distances
    for (int idx = tid; idx < KNB * 25; idx += 256) {
        int k = idx / 25;
        int p = idx - k * 25;
        const float* Ai = &atoms[PAIR_I_d[p] * 3];
        const float* Aj = &atoms[(1 + k) * 15 + PAIR_J_d[p] * 3];
        float dx = Ai[0] - Aj[0], dy = Ai[1] - Aj[1], dz = Ai[2] - Aj[2];
        dist[idx] = sqrtf(dx * dx + dy * dy + dz * dz + 1e-6f);
    }
    __syncthreads();

    // step 3: feature matrix f[32][416]
    for (int idx = tid; idx < 32 * EDGE_IN; idx += 256) {
        int k = idx / EDGE_IN;
        int t = idx - k * EDGE_IN;
        float v = 0.0f;
        if (k < KNB) {
            if (t < NPOS) {
                v = W_pos[dclip[k] * NPOS + t] + b_pos[t];
            } else {
                int q = t - NPOS;
                int p = q >> 4;
                int r = q & 15;
                float mu = 2.0f + (20.0f / 15.0f) * (float)r;
                float x = (dist[k * 25 + p] - mu) * 0.8f;   // / sigma=1.25
                v = expf(-x * x);
            }
        }
        f[idx] = v;
    }
    __syncthreads();

    // step 4: GEMM — thread handles 4 edges (ky, ky+8, ky+16, ky+24) x 4 cols
    int cg = tid & 31;
    int ky = tid >> 5;        // 0..7
    int c0 = cg * 4;
    float acc[4][4] = {{0.f}};
    const float* fp0 = &f[(ky + 0) * EDGE_IN];
    const float* fp1 = &f[(ky + 8) * EDGE_IN];
    const float* fp2 = &f[(ky + 16) * EDGE_IN];
    const float* fp3 = &f[(ky + 24) * EDGE_IN];
    const float* W = W_edge + c0;
#pragma unroll 4
    for (int t = 0; t < EDGE_IN; ++t) {
        float4 w = *(const float4*)(W + t * EDGE_C);
        float f0 = fp0[t], f1 = fp1[t], f2 = fp2[t], f3 = fp3[t];
        acc[0][0] += f0 * w.x; acc[0][1] += f0 * w.y; acc[0][2] += f0 * w.z; acc[0][3] += f0 * w.w;
        acc[1][0] += f1 * w.x; acc[1][1] += f1 * w.y; acc[1][2] += f1 * w.z; acc[1][3] += f1 * w.w;
        acc[2][0] += f2 * w.x; acc[2][1] += f2 * w.y; acc[2][2] += f2 * w.z; acc[2][3] += f2 * w.w;
        acc[3][0] += f3 * w.x; acc[3][1] += f3 * w.y; acc[3][2] += f3 * w.z; acc[3][3] += f3 * w.w;
    }

    float gam[4], bet[4];
#pragma unroll
    for (int c = 0; c < 4; ++c) { gam[c] = gamma[c0 + c]; bet[c] = beta[c0 + c]; }

    // LayerNorm per edge across the 32 lanes sharing ky (xor masks < 32 stay in-group)
#pragma unroll
    for (int r2 = 0; r2 < 4; ++r2) {
        int e = ky + 8 * r2;
        float s = acc[r2][0] + acc[r2][1] + acc[r2][2] + acc[r2][3];
        for (int o = 16; o; o >>= 1) s += __shfl_xor(s, o);
        float mean = s * (1.0f / 128.0f);
        float vs = 0.0f;
#pragma unroll
        for (int c = 0; c < 4; ++c) { float d = acc[r2][c] - mean; vs += d * d; }
        for (int o = 16; o; o >>= 1) vs += __shfl_xor(vs, o);
        float inv = 1.0f / sqrtf(vs * (1.0f / 128.0f) + 1e-5f);
        if (e < KNB) {
            float4 o4;
            o4.x = (acc[r2][0] - mean) * inv * gam[0] + bet[0];
            o4.y = (acc[r2][1] - mean) * inv * gam[1] + bet[1];
            o4.z = (acc[r2][2] - mean) * inv * gam[2] + bet[2];
            o4.w = (acc[r2][3] - mean) * inv * gam[3] + bet[3];
            *(float4*)(out_E + ((size_t)(row * KNB + e)) * EDGE_C + c0) = o4;
        }
    }
}

extern "C" void kernel_launch(void* const* d_in, const int* in_sizes, int n_in,
                              void* d_out, int out_size, void* d_ws, size_t ws_size,
                              hipStream_t stream) {
    const float* X      = (const float*)d_in[0];
    const float* mask   = (const float*)d_in[1];
    const int*   ridx   = (const int*)d_in[2];
    // d_in[3..5] = S, SSE3_seq, SSE8_seq — unused by the reference forward
    const float* W_pos  = (const float*)d_in[6];
    const float* b_pos  = (const float*)d_in[7];
    const float* W_edge = (const float*)d_in[8];
    const float* gamma  = (const float*)d_in[9];
    const float* beta   = (const float*)d_in[10];

    float* out_E   = (float*)d_out;
    float* out_idx = out_E + (size_t)BB * LL * KNB * EDGE_C;   // E_idx stored as floats

    knn_kernel<<<BB * LL, 64, 0, stream>>>(X, mask, out_idx);
    edge_kernel<<<BB * LL, 256, 0, stream>>>(X, ridx, W_pos, b_pos, W_edge,
                                             gamma, beta, out_idx, out_E);
}

// Round 2
// 293.133 us; speedup vs baseline: 2.7986x; 2.7986x over previous
//
#include <hip/hip_runtime.h>

// Problem constants
#define BB 8
#define LL 1024
#define KNB 30
#define NUM_RBF 16
#define NPOS 16
#define MAXREL 32
#define EDGE_C 128
#define EDGE_IN 416   // NPOS + 25*NUM_RBF
#define NKK 26        // 416 / 16 K-steps for 32x32x16 MFMA

__constant__ int PAIR_I_d[25] = {0,1,2,3,4,0,0,0,0,1,1,1,4,4,3,1,2,3,4,2,3,4,2,3,2};
__constant__ int PAIR_J_d[25] = {0,1,2,3,4,1,2,3,4,2,3,4,2,3,2,0,0,0,0,1,1,1,4,4,3};

typedef _Float16 half8 __attribute__((ext_vector_type(8)));
typedef float floatx16 __attribute__((ext_vector_type(16)));

__device__ __forceinline__ unsigned long long shfl_down_u64(unsigned long long v, int o) {
    unsigned int lo = (unsigned int)(v & 0xFFFFFFFFull);
    unsigned int hi = (unsigned int)(v >> 32);
    lo = __shfl_down(lo, o);
    hi = __shfl_down(hi, o);
    return ((unsigned long long)hi << 32) | lo;
}
__device__ __forceinline__ unsigned long long shfl_bcast_u64(unsigned long long v, int src) {
    unsigned int lo = (unsigned int)(v & 0xFFFFFFFFull);
    unsigned int hi = (unsigned int)(v >> 32);
    lo = __shfl(lo, src);
    hi = __shfl(hi, src);
    return ((unsigned long long)hi << 32) | lo;
}

// -------- Kernel 0: repack W_edge (416x128 f32) into fragment-linear fp16 --------
// WtF[((kk*4 + w)*64 + l)*8 + j] = W_edge[(kk*16 + (l>>5)*8 + j)*128 + w*32 + (l&31)]
__global__ __launch_bounds__(256) void wprep_kernel(const float* __restrict__ W_edge,
                                                    _Float16* __restrict__ WtF) {
    int o = blockIdx.x * 256 + threadIdx.x;   // 26*4*64*8 = 53248 total
    if (o >= NKK * 4 * 64 * 8) return;
    int j  = o & 7;
    int l  = (o >> 3) & 63;
    int w  = (o >> 9) & 3;
    int kk = o >> 11;
    int k  = (kk << 4) + ((l >> 5) << 3) + j;
    int n  = (w << 5) + (l & 31);
    WtF[o] = (_Float16)W_edge[k * EDGE_C + n];
}

// -------- Kernel 1: kNN (4 rows per 256-thread block; one wave per row) --------
__global__ __launch_bounds__(256) void knn_kernel(const float* __restrict__ X,
                                                  const float* __restrict__ mask,
                                                  float* __restrict__ out_idx) {
    int b  = blockIdx.x >> 8;                 // 2048 blocks; 256 blocks per batch
    int i0 = (blockIdx.x & 255) * 4;
    int tid = threadIdx.x;
    int lane = tid & 63;
    int wv = tid >> 6;

    __shared__ float sCa[LL * 3];
    __shared__ float sMask[LL];

    for (int j = tid; j < LL; j += 256) {
        int base = (b * LL + j) * 12 + 3;     // Ca
        sCa[j * 3 + 0] = X[base + 0];
        sCa[j * 3 + 1] = X[base + 1];
        sCa[j * 3 + 2] = X[base + 2];
        sMask[j] = mask[b * LL + j];
    }
    __syncthreads();

    int i = i0 + wv;
    int row = b * LL + i;
    float cax = sCa[i * 3 + 0], cay = sCa[i * 3 + 1], caz = sCa[i * 3 + 2];
    float mi = sMask[i];

    float Dloc[16];
    float dmax = 0.0f;
#pragma unroll
    for (int c = 0; c < 16; ++c) {
        int j = lane + c * 64;
        float dx = cax - sCa[j * 3 + 0];
        float dy = cay - sCa[j * 3 + 1];
        float dz = caz - sCa[j * 3 + 2];
        float m2 = mi * sMask[j];
        float D = m2 * sqrtf(dx * dx + dy * dy + dz * dz + 1e-6f);
        Dloc[c] = D;
        dmax = fmaxf(dmax, D);
    }
    for (int o = 32; o; o >>= 1) dmax = fmaxf(dmax, __shfl_down(dmax, o));
    dmax = __shfl(dmax, 0);

    unsigned long long packed[16];
#pragma unroll
    for (int c = 0; c < 16; ++c) {
        int j = lane + c * 64;
        float m2 = mi * sMask[j];
        float Dadj = Dloc[c] + (1.0f - m2) * dmax;
        unsigned int bits = __float_as_uint(Dadj);
        packed[c] = ((unsigned long long)bits << 32) | (unsigned int)j;
    }

    float* dst = out_idx + (size_t)row * KNB;
    for (int r = 0; r < KNB; ++r) {
        unsigned long long best = packed[0];
#pragma unroll
        for (int c = 1; c < 16; ++c) best = (packed[c] < best) ? packed[c] : best;
        for (int o = 32; o; o >>= 1) {
            unsigned long long other = shfl_down_u64(best, o);
            best = (other < best) ? other : best;
        }
        best = shfl_bcast_u64(best, 0);
        unsigned int jwin = (unsigned int)(best & 0xFFFFFFFFull);
#pragma unroll
        for (int c = 0; c < 16; ++c) {
            if ((unsigned int)(lane + c * 64) == jwin) packed[c] = ~0ull;
        }
        if (lane == 0) dst[r] = (float)jwin;
    }
}

// -------- Kernel 2: features -> MFMA f16 GEMM -> LayerNorm, one block per (b,i) --------
__global__ __launch_bounds__(256) void edge_kernel(const float* __restrict__ X,
                                                   const int* __restrict__ ridx,
                                                   const float* __restrict__ W_pos,
                                                   const float* __restrict__ b_pos,
                                                   const _Float16* __restrict__ WtF,
                                                   const float* __restrict__ gamma,
                                                   const float* __restrict__ beta,
                                                   const float* __restrict__ out_idx,
                                                   float* __restrict__ out_E) {
    int row = blockIdx.x;   // b*L + i
    int b = row >> 10;
    int i = row & 1023;
    int tid = threadIdx.x;

    // fA (A-fragments, fp16, 26*64*8 = 26624 B) overlaid with Esh (32x128 f32 = 16384 B)
    __shared__ __align__(16) char smem[NKK * 64 * 8 * 2];
    _Float16* fA = (_Float16*)smem;
    float* Esh = (float*)smem;

    __shared__ float atoms[31 * 15];
    __shared__ float dist[KNB * 25];
    __shared__ int nbr[KNB];
    __shared__ int dclip[KNB];

    // step 0: neighbor indices + positional bucket
    if (tid < KNB) {
        int jn = (int)out_idx[(size_t)row * KNB + tid];
        nbr[tid] = jn;
        int off = ridx[row] - ridx[b * LL + jn];
        int d = off + MAXREL;
        d = d < 0 ? 0 : (d > 2 * MAXREL ? 2 * MAXREL : d);
        dclip[tid] = d;
    }
    __syncthreads();

    // step 1: atoms for residue i and its 30 neighbors
    if (tid < 31) {
        int r = (tid == 0) ? i : nbr[tid - 1];
        int base = (b * LL + r) * 12;
        float Nx = X[base + 0], Ny = X[base + 1], Nz = X[base + 2];
        float Cax = X[base + 3], Cay = X[base + 4], Caz = X[base + 5];
        float Cx = X[base + 6], Cy = X[base + 7], Cz = X[base + 8];
        float Ox = X[base + 9], Oy = X[base + 10], Oz = X[base + 11];
        float bx = Cax - Nx, by = Cay - Ny, bz = Caz - Nz;
        float cx = Cx - Cax, cy = Cy - Cay, cz = Cz - Caz;
        float ax = by * cz - bz * cy;
        float ay = bz * cx - bx * cz;
        float az = bx * cy - by * cx;
        float Cbx = -0.58273431f * ax + 0.56802827f * bx - 0.54067466f * cx + Cax;
        float Cby = -0.58273431f * ay + 0.56802827f * by - 0.54067466f * cy + Cay;
        float Cbz = -0.58273431f * az + 0.56802827f * bz - 0.54067466f * cz + Caz;
        float* A = &atoms[tid * 15];
        A[0] = Cax; A[1] = Cay; A[2] = Caz;
        A[3] = Nx;  A[4] = Ny;  A[5] = Nz;
        A[6] = Cx;  A[7] = Cy;  A[8] = Cz;
        A[9] = Ox;  A[10] = Oy; A[11] = Oz;
        A[12] = Cbx; A[13] = Cby; A[14] = Cbz;
    }
    __syncthreads();

    // step 2: 30*25 atom-pair distances
    for (int idx = tid; idx < KNB * 25; idx += 256) {
        int k = idx / 25;
        int p = idx - k * 25;
        const float* Ai = &atoms[PAIR_I_d[p] * 3];
        const float* Aj = &atoms[(1 + k) * 15 + PAIR_J_d[p] * 3];
        float dx = Ai[0] - Aj[0], dy = Ai[1] - Aj[1], dz = Ai[2] - Aj[2];
        dist[idx] = sqrtf(dx * dx + dy * dy + dz * dz + 1e-6f);
    }
    __syncthreads();

    // step 3: build A-fragments in MFMA order, 8 k at a time (one ds_write_b128 each)
    // element (m,k): fA[((k>>4)*64 + m + 32*((k>>3)&1))*8 + (k&7)]
    for (int it = tid; it < 32 * 52; it += 256) {
        int m = it / 52;
        int kg = it - m * 52;
        int k0 = kg * 8;
        half8 v8;
        if (m >= KNB) {
            #pragma unroll
            for (int jj = 0; jj < 8; ++jj) v8[jj] = (_Float16)0.0f;
        } else if (kg < 2) {
            const float* wp = &W_pos[dclip[m] * NPOS + k0];
            const float* bp = &b_pos[k0];
            #pragma unroll
            for (int jj = 0; jj < 8; ++jj) v8[jj] = (_Float16)(wp[jj] + bp[jj]);
        } else {
            int q0 = k0 - NPOS;
            int p = q0 >> 4;            // constant over the 8 elements
            int r0 = q0 & 15;           // 0 or 8
            float dd = dist[m * 25 + p];
            #pragma unroll
            for (int jj = 0; jj < 8; ++jj) {
                float mu = 2.0f + (20.0f / 15.0f) * (float)(r0 + jj);
                float x = (dd - mu) * 0.8f;    // / sigma = 1.25
                v8[jj] = (_Float16)expf(-x * x);
            }
        }
        int pos = ((kg >> 1) * 64 + m + 32 * (kg & 1)) * 8;
        *(half8*)(fA + pos) = v8;
    }
    __syncthreads();

    // step 4: MFMA K-loop. wave wv computes 32 rows x cols [32wv, 32wv+32)
    int wv = tid >> 6;
    int l = tid & 63;
    floatx16 acc;
#pragma unroll
    for (int r = 0; r < 16; ++r) acc[r] = 0.0f;

    const half8* Ap = (const half8*)fA + l;              // + kk*64
    const half8* Bp = (const half8*)WtF + wv * 64 + l;   // + kk*256
#pragma unroll 4
    for (int kk = 0; kk < NKK; ++kk) {
        half8 a = Ap[kk * 64];
        half8 bfr = Bp[kk * 256];
        acc = __builtin_amdgcn_mfma_f32_32x32x16_f16(a, bfr, acc, 0, 0, 0);
    }
    __syncthreads();   // everyone done reading fA before overlay write

    // step 5: spill C to LDS (C layout: col=l&31, row=(r&3)+8*(r>>2)+4*(l>>5))
#pragma unroll
    for (int r = 0; r < 16; ++r) {
        int rr = (r & 3) + 8 * (r >> 2) + 4 * (l >> 5);
        Esh[rr * EDGE_C + wv * 32 + (l & 31)] = acc[r];
    }
    __syncthreads();

    // step 6: LayerNorm; thread (ky=tid>>5, cg=tid&31) handles rows ky+8*{0..3}, cols cg*4..+3
    int cg = tid & 31;
    int ky = tid >> 5;
    int c0 = cg * 4;
    float gam[4], bet[4];
#pragma unroll
    for (int c = 0; c < 4; ++c) { gam[c] = gamma[c0 + c]; bet[c] = beta[c0 + c]; }

#pragma unroll
    for (int r2 = 0; r2 < 4; ++r2) {
        int e = ky + 8 * r2;
        float v0 = Esh[e * EDGE_C + c0 + 0];
        float v1 = Esh[e * EDGE_C + c0 + 1];
        float v2 = Esh[e * EDGE_C + c0 + 2];
        float v3 = Esh[e * EDGE_C + c0 + 3];
        float s = v0 + v1 + v2 + v3;
        for (int o = 16; o; o >>= 1) s += __shfl_xor(s, o);
        float mean = s * (1.0f / 128.0f);
        float d0 = v0 - mean, d1 = v1 - mean, d2 = v2 - mean, d3 = v3 - mean;
        float vs = d0 * d0 + d1 * d1 + d2 * d2 + d3 * d3;
        for (int o = 16; o; o >>= 1) vs += __shfl_xor(vs, o);
        float inv = 1.0f / sqrtf(vs * (1.0f / 128.0f) + 1e-5f);
        if (e < KNB) {
            float4 o4;
            o4.x = d0 * inv * gam[0] + bet[0];
            o4.y = d1 * inv * gam[1] + bet[1];
            o4.z = d2 * inv * gam[2] + bet[2];
            o4.w = d3 * inv * gam[3] + bet[3];
            *(float4*)(out_E + ((size_t)(row * KNB + e)) * EDGE_C + c0) = o4;
        }
    }
}

extern "C" void kernel_launch(void* const* d_in, const int* in_sizes, int n_in,
                              void* d_out, int out_size, void* d_ws, size_t ws_size,
                              hipStream_t stream) {
    const float* X      = (const float*)d_in[0];
    const float* mask   = (const float*)d_in[1];
    const int*   ridx   = (const int*)d_in[2];
    const float* W_pos  = (const float*)d_in[6];
    const float* b_pos  = (const float*)d_in[7];
    const float* W_edge = (const float*)d_in[8];
    const float* gamma  = (const float*)d_in[9];
    const float* beta   = (const float*)d_in[10];

    float* out_E   = (float*)d_out;
    float* out_idx = out_E + (size_t)BB * LL * KNB * EDGE_C;   // E_idx stored as floats
    _Float16* WtF  = (_Float16*)d_ws;                          // 106 KB fragment-linear W

    wprep_kernel<<<(NKK * 4 * 64 * 8 + 255) / 256, 256, 0, stream>>>(W_edge, WtF);
    knn_kernel<<<BB * LL / 4, 256, 0, stream>>>(X, mask, out_idx);
    edge_kernel<<<BB * LL, 256, 0, stream>>>(X, ridx, W_pos, b_pos, WtF,
                                             gamma, beta, out_idx, out_E);
}

// Round 3
// 257.162 us; speedup vs baseline: 3.1900x; 1.1399x over previous
//
#include <hip/hip_runtime.h>

// Problem constants
#define BB 8
#define LL 1024
#define KNB 30
#define NUM_RBF 16
#define NPOS 16
#define MAXREL 32
#define EDGE_C 128
#define EDGE_IN 416   // NPOS + 25*NUM_RBF
#define NKK 26        // 416 / 16 K-steps for 32x32x16 MFMA
#define WTF_N (NKK * 4 * 64 * 8)   // 53248 fp16 elements

__constant__ int PAIR_I_d[25] = {0,1,2,3,4,0,0,0,0,1,1,1,4,4,3,1,2,3,4,2,3,4,2,3,2};
__constant__ int PAIR_J_d[25] = {0,1,2,3,4,1,2,3,4,2,3,4,2,3,2,0,0,0,0,1,1,1,4,4,3};

typedef _Float16 half8 __attribute__((ext_vector_type(8)));
typedef float floatx16 __attribute__((ext_vector_type(16)));

// -------- Kernel 1: kNN (4 rows per 256-thread block; one wave per row) --------
// Blocks >= 2048 instead repack W_edge into fragment-linear fp16 (folded wprep).
__global__ __launch_bounds__(256) void knn_kernel(const float* __restrict__ X,
                                                  const float* __restrict__ mask,
                                                  float* __restrict__ out_idx,
                                                  const float* __restrict__ W_edge,
                                                  _Float16* __restrict__ WtF) {
    if (blockIdx.x >= 2048) {
        // WtF[((kk*4+w)*64+l)*8+j] = W_edge[(kk*16+(l>>5)*8+j)*128 + w*32+(l&31)]
        int o = (blockIdx.x - 2048) * 256 + threadIdx.x;
        if (o < WTF_N) {
            int j = o & 7, l = (o >> 3) & 63, w = (o >> 9) & 3, kk = o >> 11;
            int k = (kk << 4) + ((l >> 5) << 3) + j;
            int n = (w << 5) + (l & 31);
            WtF[o] = (_Float16)W_edge[k * EDGE_C + n];
        }
        return;
    }

    int b = blockIdx.x >> 8;
    int i0 = (blockIdx.x & 255) * 4;
    int tid = threadIdx.x;
    int lane = tid & 63;
    int wv = tid >> 6;

    __shared__ float sCa[LL * 3];
    __shared__ float sMask[LL];

    for (int j = tid; j < LL; j += 256) {
        int base = (b * LL + j) * 12 + 3;     // Ca
        sCa[j * 3 + 0] = X[base + 0];
        sCa[j * 3 + 1] = X[base + 1];
        sCa[j * 3 + 2] = X[base + 2];
        sMask[j] = mask[b * LL + j];
    }
    __syncthreads();

    int i = i0 + wv;
    int row = b * LL + i;
    float cax = sCa[i * 3 + 0], cay = sCa[i * 3 + 1], caz = sCa[i * 3 + 2];
    float mi = sMask[i];

    float Dv[16];
    float dmax = 0.0f;
#pragma unroll
    for (int c = 0; c < 16; ++c) {
        int j = lane + c * 64;
        float dx = cax - sCa[j * 3 + 0];
        float dy = cay - sCa[j * 3 + 1];
        float dz = caz - sCa[j * 3 + 2];
        float m2 = mi * sMask[j];
        float D = m2 * sqrtf(dx * dx + dy * dy + dz * dz + 1e-6f);
        Dv[c] = D;
        dmax = fmaxf(dmax, D);
    }
    for (int o = 32; o; o >>= 1) dmax = fmaxf(dmax, __shfl_down(dmax, o));
    dmax = __shfl(dmax, 0);

    // exact sortable key: Dadj_bits * 1024 + j  (< 2^41, exact in f64)
    double cand[16];
#pragma unroll
    for (int c = 0; c < 16; ++c) {
        int j = lane + c * 64;
        float m2 = mi * sMask[j];
        float Dadj = Dv[c] + (1.0f - m2) * dmax;
        unsigned int bits = __float_as_uint(Dadj);
        cand[c] = fma((double)bits, 1024.0, (double)j);
    }

    const double KILL = 9.0e15;
    float myj = 0.0f;
    for (int r = 0; r < KNB; ++r) {
        // lane-local min: balanced fmin tree (v_min_f64)
        double a0 = fmin(cand[0], cand[1]);
        double a1 = fmin(cand[2], cand[3]);
        double a2 = fmin(cand[4], cand[5]);
        double a3 = fmin(cand[6], cand[7]);
        double a4 = fmin(cand[8], cand[9]);
        double a5 = fmin(cand[10], cand[11]);
        double a6 = fmin(cand[12], cand[13]);
        double a7 = fmin(cand[14], cand[15]);
        a0 = fmin(a0, a1); a2 = fmin(a2, a3); a4 = fmin(a4, a5); a6 = fmin(a6, a7);
        a0 = fmin(a0, a2); a4 = fmin(a4, a6);
        double m = fmin(a0, a4);
        // wave min
        for (int o = 32; o; o >>= 1) {
            double other = __shfl_down(m, o);
            m = fmin(m, other);
        }
        m = __shfl(m, 0);
        unsigned long long ku = (unsigned long long)m;   // exact
        int jw = __builtin_amdgcn_readfirstlane((int)(ku & 1023));
        bool own = (lane == (jw & 63));
        switch (jw >> 6) {   // scalar 16-way branch; one masked v_mov pair
            case 0:  if (own) cand[0]  = KILL; break;
            case 1:  if (own) cand[1]  = KILL; break;
            case 2:  if (own) cand[2]  = KILL; break;
            case 3:  if (own) cand[3]  = KILL; break;
            case 4:  if (own) cand[4]  = KILL; break;
            case 5:  if (own) cand[5]  = KILL; break;
            case 6:  if (own) cand[6]  = KILL; break;
            case 7:  if (own) cand[7]  = KILL; break;
            case 8:  if (own) cand[8]  = KILL; break;
            case 9:  if (own) cand[9]  = KILL; break;
            case 10: if (own) cand[10] = KILL; break;
            case 11: if (own) cand[11] = KILL; break;
            case 12: if (own) cand[12] = KILL; break;
            case 13: if (own) cand[13] = KILL; break;
            case 14: if (own) cand[14] = KILL; break;
            case 15: if (own) cand[15] = KILL; break;
        }
        if (lane == r) myj = (float)jw;
    }
    if (lane < KNB) out_idx[(size_t)row * KNB + lane] = myj;
}

// -------- Kernel 2: features -> MFMA f16 GEMM -> LayerNorm, one block per (b,i) --------
__global__ __launch_bounds__(256) void edge_kernel(const float* __restrict__ X,
                                                   const int* __restrict__ ridx,
                                                   const float* __restrict__ W_pos,
                                                   const float* __restrict__ b_pos,
                                                   const _Float16* __restrict__ WtF,
                                                   const float* __restrict__ gamma,
                                                   const float* __restrict__ beta,
                                                   const float* __restrict__ out_idx,
                                                   float* __restrict__ out_E) {
    int row = blockIdx.x;   // b*L + i
    int b = row >> 10;
    int i = row & 1023;
    int tid = threadIdx.x;

    // LDS overlay:
    //  [0, 26624)      fA  (A-fragments fp16)  / Esh (32x128 f32, after MFMA) / atoms (steps 1-2)
    //  [26624, 29624)  dist (30*25 f32)
    //  [29624, 29744)  nbr
    //  [29744, 29864)  dclip
    __shared__ __align__(16) char smem[29872];
    _Float16* fA = (_Float16*)smem;
    float* Esh = (float*)smem;
    float* atoms = (float*)smem;               // 31*15 f32, dead before fA is written
    float* dist = (float*)(smem + 26624);
    int* nbr = (int*)(smem + 29624);
    int* dclip = (int*)(smem + 29744);

    // step 0: neighbor indices + positional bucket
    if (tid < KNB) {
        int jn = (int)out_idx[(size_t)row * KNB + tid];
        nbr[tid] = jn;
        int off = ridx[row] - ridx[b * LL + jn];
        int d = off + MAXREL;
        d = d < 0 ? 0 : (d > 2 * MAXREL ? 2 * MAXREL : d);
        dclip[tid] = d;
    }
    __syncthreads();

    // step 1: atoms for residue i and its 30 neighbors
    if (tid < 31) {
        int r = (tid == 0) ? i : nbr[tid - 1];
        int base = (b * LL + r) * 12;
        float Nx = X[base + 0], Ny = X[base + 1], Nz = X[base + 2];
        float Cax = X[base + 3], Cay = X[base + 4], Caz = X[base + 5];
        float Cx = X[base + 6], Cy = X[base + 7], Cz = X[base + 8];
        float Ox = X[base + 9], Oy = X[base + 10], Oz = X[base + 11];
        float bx = Cax - Nx, by = Cay - Ny, bz = Caz - Nz;
        float cx = Cx - Cax, cy = Cy - Cay, cz = Cz - Caz;
        float ax = by * cz - bz * cy;
        float ay = bz * cx - bx * cz;
        float az = bx * cy - by * cx;
        float Cbx = -0.58273431f * ax + 0.56802827f * bx - 0.54067466f * cx + Cax;
        float Cby = -0.58273431f * ay + 0.56802827f * by - 0.54067466f * cy + Cay;
        float Cbz = -0.58273431f * az + 0.56802827f * bz - 0.54067466f * cz + Caz;
        float* A = &atoms[tid * 15];
        A[0] = Cax; A[1] = Cay; A[2] = Caz;
        A[3] = Nx;  A[4] = Ny;  A[5] = Nz;
        A[6] = Cx;  A[7] = Cy;  A[8] = Cz;
        A[9] = Ox;  A[10] = Oy; A[11] = Oz;
        A[12] = Cbx; A[13] = Cby; A[14] = Cbz;
    }
    __syncthreads();

    // step 2: 30*25 atom-pair distances
    for (int idx = tid; idx < KNB * 25; idx += 256) {
        int k = idx / 25;
        int p = idx - k * 25;
        const float* Ai = &atoms[PAIR_I_d[p] * 3];
        const float* Aj = &atoms[(1 + k) * 15 + PAIR_J_d[p] * 3];
        float dx = Ai[0] - Aj[0], dy = Ai[1] - Aj[1], dz = Ai[2] - Aj[2];
        dist[idx] = sqrtf(dx * dx + dy * dy + dz * dz + 1e-6f);
    }
    __syncthreads();

    // step 3: build A-fragments in MFMA order.
    // element (m,k): fA[((k>>4)*64 + m + 32*((k>>3)&1))*8 + (k&7)]
    // mapping: m = tid&31 (lane-consecutive -> conflict-free ds_write_b128), kg chunk of 8 k's
    {
        int m = tid & 31;
        int kgb = tid >> 5;          // 0..7
#pragma unroll
        for (int r = 0; r < 7; ++r) {
            int kg = kgb + 8 * r;
            if (kg < 52) {
                half8 v8;
                if (m >= KNB) {
#pragma unroll
                    for (int jj = 0; jj < 8; ++jj) v8[jj] = (_Float16)0.0f;
                } else if (kg < 2) {
                    const float* wp = &W_pos[dclip[m] * NPOS + kg * 8];
                    const float* bp = &b_pos[kg * 8];
#pragma unroll
                    for (int jj = 0; jj < 8; ++jj) v8[jj] = (_Float16)(wp[jj] + bp[jj]);
                } else {
                    int q0 = kg * 8 - 16;
                    int p = q0 >> 4;                     // atom-pair index
                    // x = 0.8*d - 1.6 - 1.0666667*(r0+jj), r0 = q0&8
                    float t = 0.8f * dist[m * 25 + p] - 1.6f - ((q0 & 8) ? 8.5333336f : 0.0f);
#pragma unroll
                    for (int jj = 0; jj < 8; ++jj) {
                        float x = t - 1.0666667f * (float)jj;
                        v8[jj] = (_Float16)__expf(-x * x);
                    }
                }
                int pos = ((kg >> 1) * 64 + m + 32 * (kg & 1)) * 8;
                *(half8*)(fA + pos) = v8;
            }
        }
    }
    __syncthreads();

    // step 4: MFMA K-loop. wave wv computes 32 rows x cols [32wv, 32wv+32)
    int wv = tid >> 6;
    int l = tid & 63;
    floatx16 acc;
#pragma unroll
    for (int r = 0; r < 16; ++r) acc[r] = 0.0f;

    const half8* Ap = (const half8*)fA + l;              // + kk*64
    const half8* Bp = (const half8*)WtF + wv * 64 + l;   // + kk*256
#pragma unroll 4
    for (int kk = 0; kk < NKK; ++kk) {
        half8 a = Ap[kk * 64];
        half8 bfr = Bp[kk * 256];
        acc = __builtin_amdgcn_mfma_f32_32x32x16_f16(a, bfr, acc, 0, 0, 0);
    }
    __syncthreads();   // everyone done reading fA before overlay write

    // step 5: spill C to LDS (C layout: col=l&31, row=(r&3)+8*(r>>2)+4*(l>>5))
#pragma unroll
    for (int r = 0; r < 16; ++r) {
        int rr = (r & 3) + 8 * (r >> 2) + 4 * (l >> 5);
        Esh[rr * EDGE_C + wv * 32 + (l & 31)] = acc[r];
    }
    __syncthreads();

    // step 6: LayerNorm; thread (ky=tid>>5, cg=tid&31) handles rows ky+8*{0..3}, cols cg*4..+3
    int cg = tid & 31;
    int ky = tid >> 5;
    int c0 = cg * 4;
    float gam[4], bet[4];
#pragma unroll
    for (int c = 0; c < 4; ++c) { gam[c] = gamma[c0 + c]; bet[c] = beta[c0 + c]; }

#pragma unroll
    for (int r2 = 0; r2 < 4; ++r2) {
        int e = ky + 8 * r2;
        float4 v = *(const float4*)&Esh[e * EDGE_C + c0];
        float s = v.x + v.y + v.z + v.w;
        for (int o = 16; o; o >>= 1) s += __shfl_xor(s, o);
        float mean = s * (1.0f / 128.0f);
        float d0 = v.x - mean, d1 = v.y - mean, d2 = v.z - mean, d3 = v.w - mean;
        float vs = d0 * d0 + d1 * d1 + d2 * d2 + d3 * d3;
        for (int o = 16; o; o >>= 1) vs += __shfl_xor(vs, o);
        float inv = 1.0f / sqrtf(vs * (1.0f / 128.0f) + 1e-5f);
        if (e < KNB) {
            float4 o4;
            o4.x = d0 * inv * gam[0] + bet[0];
            o4.y = d1 * inv * gam[1] + bet[1];
            o4.z = d2 * inv * gam[2] + bet[2];
            o4.w = d3 * inv * gam[3] + bet[3];
            *(float4*)(out_E + ((size_t)(row * KNB + e)) * EDGE_C + c0) = o4;
        }
    }
}

extern "C" void kernel_launch(void* const* d_in, const int* in_sizes, int n_in,
                              void* d_out, int out_size, void* d_ws, size_t ws_size,
                              hipStream_t stream) {
    const float* X      = (const float*)d_in[0];
    const float* mask   = (const float*)d_in[1];
    const int*   ridx   = (const int*)d_in[2];
    const float* W_pos  = (const float*)d_in[6];
    const float* b_pos  = (const float*)d_in[7];
    const float* W_edge = (const float*)d_in[8];
    const float* gamma  = (const float*)d_in[9];
    const float* beta   = (const float*)d_in[10];

    float* out_E   = (float*)d_out;
    float* out_idx = out_E + (size_t)BB * LL * KNB * EDGE_C;   // E_idx stored as floats
    _Float16* WtF  = (_Float16*)d_ws;                          // 106 KB fragment-linear W

    int knn_grid = 2048 + (WTF_N + 255) / 256;   // kNN blocks + folded W-prep blocks
    knn_kernel<<<knn_grid, 256, 0, stream>>>(X, mask, out_idx, W_edge, WtF);
    edge_kernel<<<BB * LL, 256, 0, stream>>>(X, ridx, W_pos, b_pos, WtF,
                                             gamma, beta, out_idx, out_E);
}